// Round 8
// baseline (17652.550 us; speedup 1.0000x reference)
//
#include <hip/hip_runtime.h>
#include <stdint.h>

typedef unsigned int uint;

#define T_SEQ 512
#define D_IN 64
#define H_ 256
#define KTOT 320      // D_IN + H_
#define NTOT 1024     // 4*H_
#define MID_ 64
#define ACT_ 3
#define B_TOT 1024
#define ROWS 16       // batch rows per block
#define NBLK 64
#define THREADS 1024  // 16 waves, 4 waves/SIMD
#define KB 10         // K blocks of 32 (320/32)
#define APAD 328      // padded A-row stride (elements)
#define WP_ELEMS 40960                  // uint4 per weight plane (64 nt * 10 kb * 64)
#define WP_BYTES (WP_ELEMS * 16)        // 640 KB per plane
#define WP0_OFF 1024
#define WP1_OFF (WP0_OFF + WP_BYTES)
#define INV4096 2.44140625e-4f          // 2^-12
#define NUNIT 40                        // units per step: (kb,g) = 10*4
#define WSLOT 2048                      // bytes per unit slot (2 planes x 1KB)
#define WWRAP 6144                      // 3 slots per wave

typedef _Float16 half_t;
typedef __attribute__((ext_vector_type(8))) _Float16 half8;
typedef __attribute__((ext_vector_type(4))) float floatx4;

__device__ inline float bf2f(unsigned short s) {
  union { uint u; float f; } v; v.u = ((uint)s) << 16; return v.f;
}
union UHU { half_t h; unsigned short u; };
__device__ inline unsigned short h2u(half_t h) { UHU v; v.h = h; return v.u; }
__device__ inline half_t u2h(unsigned short u) { UHU v; v.u = u; return v.h; }
union U4H8 { uint4 u; half8 h; };
__device__ inline half8 u4h8(uint4 v) { U4H8 t; t.u = v; return t.h; }

// load input element idx as float, from fp32 or bf16 storage
__device__ inline float ldin(const void* p, int idx, int isf) {
  return isf ? ((const float*)p)[idx] : bf2f(((const unsigned short*)p)[idx]);
}

// 2-digit fp16 split with scaled residual: f ≈ d0 + d1*2^-12, rel err ~2^-22.
__device__ inline void split2h(float f, half_t& d0, half_t& d1) {
  d0 = (half_t)f;                       // RNE
  float r = f - (float)d0;              // exact in fp32
  d1 = (half_t)(r * 4096.0f);           // exact scale; RNE round
}

// force a wave-uniform pointer into SGPRs
__device__ inline const uint4* uni(const uint4* p) {
  uint64_t v = (uint64_t)p;
  uint lo = __builtin_amdgcn_readfirstlane((uint)v);
  uint hi = __builtin_amdgcn_readfirstlane((uint)(v >> 32));
  return (const uint4*)(((uint64_t)hi << 32) | lo);
}

// async global->LDS DMA, 16B/lane, zero VGPR result. LDS dest is wave-uniform
// base + lane*16 (HW rule); global src is per-lane.
__device__ inline void dma16(const uint4* gsrc_lane, void* lds_base) {
  __builtin_amdgcn_global_load_lds(
      (const __attribute__((address_space(1))) void*)gsrc_lane,
      (__attribute__((address_space(3))) void*)lds_base, 16, 0, 0);
}

// ---- dtype detector: fp32 storage => low halves of floats are mantissa junk
__global__ void detect_dtype(const unsigned short* __restrict__ x,
                             int* __restrict__ flag) {
  if (blockIdx.x == 0 && threadIdx.x == 0) {
    int f = 0;
    for (int i = 0; i < 256; ++i) {
      float v = bf2f(x[i]);
      if (!(fabsf(v) < 1e10f)) f = 1;   // catches huge, inf, NaN
    }
    *flag = f;
  }
}

// Repack Wc (KTOT x NTOT, row-major) into 2 fp16-digit MFMA B-fragment planes:
// frag index = nt*KB + kb ; element = frag*64 + lane ; lane holds
// B[k = kb*32 + (lane>>4)*8 + j][n = nt*16 + (lane&15)], j=0..7 packed in 16B.
__global__ void repack_wc(const void* __restrict__ Wc,
                          uint4* __restrict__ W0, uint4* __restrict__ W1,
                          const int* __restrict__ flag) {
  int tid = blockIdx.x * blockDim.x + threadIdx.x;  // 40960 threads
  int lane = tid & 63;
  int frag = tid >> 6;                              // 0..639
  int nt = frag / KB;
  int kb = frag - nt * KB;
  int n = nt * 16 + (lane & 15);
  int k0 = kb * 32 + (lane >> 4) * 8;
  int isf = *flag;
  unsigned short e0[8], e1[8];
#pragma unroll
  for (int j = 0; j < 8; ++j) {
    size_t idx = (size_t)(k0 + j) * NTOT + n;
    float w = isf ? ((const float*)Wc)[idx] : bf2f(((const unsigned short*)Wc)[idx]);
    half_t d0, d1;
    split2h(w, d0, d1);
    e0[j] = h2u(d0);
    e1[j] = h2u(d1);
  }
  uint4 o0, o1;
  o0.x = (uint)e0[0] | ((uint)e0[1] << 16);
  o0.y = (uint)e0[2] | ((uint)e0[3] << 16);
  o0.z = (uint)e0[4] | ((uint)e0[5] << 16);
  o0.w = (uint)e0[6] | ((uint)e0[7] << 16);
  o1.x = (uint)e1[0] | ((uint)e1[1] << 16);
  o1.y = (uint)e1[2] | ((uint)e1[3] << 16);
  o1.z = (uint)e1[4] | ((uint)e1[5] << 16);
  o1.w = (uint)e1[6] | ((uint)e1[7] << 16);
  W0[tid] = o0;
  W1[tid] = o1;
}

// W streaming via global_load_lds (zero VGPR cost) into per-wave private
// 6KB triple buffers, counted vmcnt, 2 units in flight. Rounds 2-6 proved the
// compiler will NOT pipeline VGPR-destined loads here (VGPR_Count pinned at
// 64; every load group exposed full L2 latency; 11ms invariant to source
// schedule). DMA + counted s_waitcnt takes the register allocator out of the
// loop entirely.
__global__ __launch_bounds__(THREADS) void xlstm_main(
    const void* __restrict__ xg,
    const void* __restrict__ bc,
    const uint4* __restrict__ W0, const uint4* __restrict__ W1,
    const void* __restrict__ Wa1, const void* __restrict__ ba1,
    const void* __restrict__ Wa2, const void* __restrict__ ba2,
    const void* __restrict__ Wv1, const void* __restrict__ bv1,
    const void* __restrict__ Wv2, const void* __restrict__ bv2,
    void* __restrict__ outv,
    const int* __restrict__ flagp)
{
  __shared__ unsigned short A0[2][ROWS][APAD];   // digit-0 plane [xt | h], dbuf
  __shared__ unsigned short A1[2][ROWS][APAD];   // digit-1 plane (scaled 2^12)
  __shared__ __align__(16) char WBraw[16 * WWRAP];  // 96KB W staging (16 waves x 3 slots x 2KB)
  __shared__ float mida[ROWS][MID_ + 2];
  __shared__ float midv[ROWS][MID_ + 2];
  __shared__ float lgts[ROWS][4];

  const int tid = threadIdx.x;
  const int lane = tid & 63;
  const int wave = tid >> 6;                     // 0..15
  const int b0 = blockIdx.x * ROWS;
  const int isf = *flagp;                        // uniform
  char* const wbbase = WBraw + wave * WWRAP;     // this wave's private 6KB

  // zero h-section of both planes of buffer 0 (h0 = 0): 4 shorts per thread
  {
    int r = tid >> 6;                            // 0..15
    int c0 = 64 + (tid & 63) * 4;                // 64..316
    *(uint2*)&A0[0][r][c0] = make_uint2(0u, 0u);
    *(uint2*)&A1[0][r][c0] = make_uint2(0u, 0u);
  }

  // x staging: each thread owns exactly 1 x element of one row per step
  const int xr = tid >> 6;                       // row 0..15
  const int xcol = tid & 63;                     // col 0..63
  const unsigned short* xu_base =
      (const unsigned short*)xg + ((size_t)(b0 + xr) * T_SEQ) * 64 + xcol;
  const float* xf_base =
      (const float*)xg + ((size_t)(b0 + xr) * T_SEQ) * 64 + xcol;
  unsigned short x0, x1;
  {
    float a = isf ? xf_base[0] : bf2f(xu_base[0]);
    half_t d0, d1;
    split2h(a, d0, d1);
    x0 = h2u(d0); x1 = h2u(d1);
  }

  const int l15 = lane & 15;
  const int quad = lane >> 4;
  const int crow = quad * 4;                     // C-layout row base
  const int u = wave * 16 + l15;                 // hidden unit owned by this lane

  const float bi  = ldin(bc, u, isf);
  const float bfg = ldin(bc, H_ + u, isf);
  const float bo  = ldin(bc, 2 * H_ + u, isf);
  const float bz  = ldin(bc, 3 * H_ + u, isf);

  // W stream bases (wave-uniform, SGPR). Wave owns tiles nt = g*16 + wave.
  const uint4* bp0[4];
  const uint4* bp1[4];
#pragma unroll
  for (int g = 0; g < 4; ++g) {
    const size_t toff = (size_t)((g * 16 + wave) * KB) * 64;
    bp0[g] = uni(W0 + toff);
    bp1[g] = uni(W1 + toff);
  }

  float cst[4], nst[4];
#pragma unroll
  for (int r = 0; r < 4; ++r) { cst[r] = 0.f; nst[r] = 1.f; }

  // DMA prologue: units 0 (kb0,g0) and 1 (kb0,g1) into slots 0,1.
  // Unit stream is t-invariant (same W every step), so the pipeline wraps
  // across step boundaries with a persistent rotating slot offset.
  dma16(bp0[0] + lane, wbbase + 0);
  dma16(bp1[0] + lane, wbbase + 0 + 1024);
  dma16(bp0[1] + lane, wbbase + WSLOT);
  dma16(bp1[1] + lane, wbbase + WSLOT + 1024);
  uint co = 0;                                   // consume slot byte offset

  for (int t = 0; t < T_SEQ; ++t) {
    const int cur = t & 1, nxt = cur ^ 1;
    A0[cur][xr][xcol] = x0;                      // write x(t) digits
    A1[cur][xr][xcol] = x1;
    // the ONLY per-step barrier: A-plane (x + h digits) visibility.
    // vmcnt NOT drained: W DMAs stay in flight across the step boundary.
    asm volatile("s_waitcnt lgkmcnt(0)\n\ts_barrier" ::: "memory");

    // issue x(t+1) load now; split after the unit loop (compiler inserts the
    // precise counted vmcnt for it, no pipeline drain)
    float xa_f = 0.f; uint xa_u = 0;
    if (t + 1 < T_SEQ) {
      if (isf) xa_f = xf_base[(size_t)(t + 1) * 64];
      else     xa_u = (uint)xu_base[(size_t)(t + 1) * 64];
    }

    // gates GEMM, 2-digit fp16 split with scaled-residual planes:
    //   gate = (a0·w0) + 2^-12 · (a0·w1' + a1'·w0)     [a1'w1' ~2^-24, dropped]
    // 40 units/step, unit = (kb,g) = 2 fragments (W0,W1). Private per-wave
    // triple buffer, always 2 units ahead, vmcnt(2) per unit (3 while the
    // step's x-load is still younger than the awaited DMAs).
    // Per-accumulator MFMA order identical to the verified kernel.
    floatx4 accA[4], accB[4];
#pragma unroll
    for (int g = 0; g < 4; ++g) {
      accA[g] = (floatx4){0.f, 0.f, 0.f, 0.f};
      accB[g] = (floatx4){0.f, 0.f, 0.f, 0.f};
    }
    half8 fa0 = {}, fa1 = {};
#pragma unroll
    for (int uu = 0; uu < NUNIT; ++uu) {
      const int kb = uu >> 2, g = uu & 3;
      // wait for unit uu's DMAs (2 younger = unit uu+1's; +1 for x at uu<2).
      // lgkmcnt(0) also fences prior-slot ds_reads before the overwrite below.
      asm volatile("s_waitcnt vmcnt(%0) lgkmcnt(0)" :: "n"((uu < 2) ? 3 : 2)
                   : "memory");
      // issue DMA for unit uu+2 (wraps to next step's units 0,1; W addresses
      // are t-invariant so the wrap is free)
      {
        const int u2 = (uu + 2 < NUNIT) ? (uu + 2) : (uu + 2 - NUNIT);
        const int kb2 = u2 >> 2, g2 = u2 & 3;
        uint dof = co + 2 * WSLOT; if (dof >= WWRAP) dof -= WWRAP;
        dma16(bp0[g2] + (size_t)kb2 * 64 + lane, wbbase + dof);
        dma16(bp1[g2] + (size_t)kb2 * 64 + lane, wbbase + dof + 1024);
      }
      // consume unit uu from slot co
      if (g == 0) {
        fa0 = u4h8(*(const uint4*)&A0[cur][l15][kb * 32 + quad * 8]);
        fa1 = u4h8(*(const uint4*)&A1[cur][l15][kb * 32 + quad * 8]);
      }
      const half8 w0 = u4h8(*(const uint4*)(wbbase + co + lane * 16));
      const half8 w1 = u4h8(*(const uint4*)(wbbase + co + 1024 + lane * 16));
      accA[g] = __builtin_amdgcn_mfma_f32_16x16x32_f16(fa0, w0, accA[g], 0, 0, 0);
      accB[g] = __builtin_amdgcn_mfma_f32_16x16x32_f16(fa1, w0, accB[g], 0, 0, 0);
      accB[g] = __builtin_amdgcn_mfma_f32_16x16x32_f16(fa0, w1, accB[g], 0, 0, 0);
      co += WSLOT; if (co >= WWRAP) co -= WWRAP;
    }

    // split the prefetched x(t+1) — latency hid under the whole unit loop
    if (t + 1 < T_SEQ) {
      float a = isf ? xa_f : bf2f((unsigned short)xa_u);
      half_t d0, d1;
      split2h(a, d0, d1);
      x0 = h2u(d0); x1 = h2u(d1);
    }

    // sLSTM update, all in registers (lane owns 4 (row,unit) pairs)
#pragma unroll
    for (int r = 0; r < 4; ++r) {
      float gi = accA[0][r] + accB[0][r] * INV4096 + bi;
      float gf = accA[1][r] + accB[1][r] * INV4096 + bfg;
      float ov = accA[2][r] + accB[2][r] * INV4096 + bo;
      float zv = accA[3][r] + accB[3][r] * INV4096 + bz;
      float iv = __expf(fminf(fmaxf(gi, -5.f), 5.f));
      float fv = __expf(fminf(fmaxf(gf, -5.f), 5.f));
      float e2z = __expf(2.f * zv);
      float tz = 1.f - 2.f / (e2z + 1.f);        // tanh, exact div
      float cv = fv * cst[r] + iv * tz;
      cv = fminf(fmaxf(cv, -1e6f), 1e6f);
      float nv = fv * nst[r] + iv;
      nv = fminf(fmaxf(nv, 1e-6f), 1e6f);
      cst[r] = cv; nst[r] = nv;
      float sg = 1.f / (1.f + __expf(-ov));      // sigmoid, exact div
      float hv = sg * (cv / nv);
      if (!(fabsf(hv) < 1e37f)) hv = 0.f;        // nan_to_num(nan/±inf -> 0)
      half_t d0, d1;
      split2h(hv, d0, d1);
      A0[nxt][crow + r][64 + u] = h2u(d0);
      A1[nxt][crow + r][64 + u] = h2u(d1);
    }
  }
  __syncthreads();                               // full drain before heads

  // ---- heads (fp32 VALU, one-time). h reconstructed from the digit planes
  // (t=511 wrote h into buffer nxt=0): h = d0 + d1*2^-12, rel err ~2^-22.
  {
    int r = tid >> 6, m = tid & 63;              // 1024 threads = 16 rows x 64
    float sa = ldin(ba1, m, isf);
    float sv = ldin(bv1, m, isf);
    for (int k = 0; k < H_; ++k) {
      float hv = (float)u2h(A0[0][r][64 + k]) +
                 (float)u2h(A1[0][r][64 + k]) * INV4096;
      sa += hv * ldin(Wa1, k * MID_ + m, isf);
      sv += hv * ldin(Wv1, k * MID_ + m, isf);
    }
    mida[r][m] = fmaxf(sa, 0.f);
    midv[r][m] = fmaxf(sv, 0.f);
  }
  __syncthreads();
  if (tid < ROWS * 4) {
    int r = tid >> 2, j = tid & 3;
    if (j < 3) {
      float s = ldin(ba2, j, isf);
      for (int m = 0; m < MID_; ++m) s += mida[r][m] * ldin(Wa2, m * ACT_ + j, isf);
      lgts[r][j] = s;
    } else {
      float s = ldin(bv2, 0, isf);
      for (int m = 0; m < MID_; ++m) s += midv[r][m] * ldin(Wv2, m, isf);
      int oi = 3 * B_TOT + b0 + r;               // value output
      if (isf) ((float*)outv)[oi] = s; else ((unsigned short*)outv)[oi] = 0;
    }
  }
  __syncthreads();
  if (tid < ROWS) {
    float l0 = lgts[tid][0], l1 = lgts[tid][1], l2 = lgts[tid][2];
    float mx = fmaxf(l0, fmaxf(l1, l2));
    float e0 = __expf(l0 - mx), e1 = __expf(l1 - mx), e2 = __expf(l2 - mx);
    float inv = 1.f / (e0 + e1 + e2);
    int oi = (b0 + tid) * 3;
    ((float*)outv)[oi + 0] = e0 * inv;
    ((float*)outv)[oi + 1] = e1 * inv;
    ((float*)outv)[oi + 2] = e2 * inv;
  }
}

extern "C" void kernel_launch(void* const* d_in, const int* in_sizes, int n_in,
                              void* d_out, int out_size, void* d_ws, size_t ws_size,
                              hipStream_t stream) {
  const void* x   = d_in[0];
  const void* Wc  = d_in[1];
  const void* bc  = d_in[2];
  const void* Wa1 = d_in[3];
  const void* ba1 = d_in[4];
  const void* Wa2 = d_in[5];
  const void* ba2 = d_in[6];
  const void* Wv1 = d_in[7];
  const void* bv1 = d_in[8];
  const void* Wv2 = d_in[9];
  const void* bv2 = d_in[10];

  int*   flag = (int*)d_ws;
  uint4* W0p  = (uint4*)((char*)d_ws + WP0_OFF);   // 640 KB digit-0 plane
  uint4* W1p  = (uint4*)((char*)d_ws + WP1_OFF);   // 640 KB scaled digit-1 plane

  detect_dtype<<<1, 64, 0, stream>>>((const unsigned short*)x, flag);
  repack_wc<<<160, 256, 0, stream>>>(Wc, W0p, W1p, flag);
  xlstm_main<<<NBLK, THREADS, 0, stream>>>(x, bc, W0p, W1p,
                                           Wa1, ba1, Wa2, ba2,
                                           Wv1, bv1, Wv2, bv2, d_out, flag);
}

// Round 10
// 14420.312 us; speedup vs baseline: 1.2241x; 1.2241x over previous
//
#include <hip/hip_runtime.h>
#include <stdint.h>

typedef unsigned int uint;

#define T_SEQ 512
#define D_IN 64
#define H_ 256
#define KTOT 320      // D_IN + H_
#define NTOT 1024     // 4*H_
#define MID_ 64
#define ACT_ 3
#define B_TOT 1024
#define ROWS 16       // batch rows per block
#define NBLK 64
#define THREADS 512   // 8 waves, 2 waves/SIMD -> 256-VGPR budget
#define KB 10         // K blocks of 32 (320/32)
#define APAD 328      // padded A-row stride (elements)
#define WP_ELEMS 40960                  // uint4 per weight plane (64 nt * 10 kb * 64)
#define WP_BYTES (WP_ELEMS * 16)        // 640 KB per plane
#define WP0_OFF 1024
#define WP1_OFF (WP0_OFF + WP_BYTES)
#define INV4096 2.44140625e-4f          // 2^-12

typedef _Float16 half_t;
typedef __attribute__((ext_vector_type(8))) _Float16 half8;
typedef __attribute__((ext_vector_type(4))) float floatx4;

__device__ inline float bf2f(unsigned short s) {
  union { uint u; float f; } v; v.u = ((uint)s) << 16; return v.f;
}
union UHU { half_t h; unsigned short u; };
__device__ inline unsigned short h2u(half_t h) { UHU v; v.h = h; return v.u; }
union U4H8 { uint4 u; half8 h; };
__device__ inline half8 u4h8(uint4 v) { U4H8 t; t.u = v; return t.h; }

// load input element idx as float, from fp32 or bf16 storage
__device__ inline float ldin(const void* p, int idx, int isf) {
  return isf ? ((const float*)p)[idx] : bf2f(((const unsigned short*)p)[idx]);
}

// 2-digit fp16 split with scaled residual: f ≈ d0 + d1*2^-12, rel err ~2^-22.
__device__ inline void split2h(float f, half_t& d0, half_t& d1) {
  d0 = (half_t)f;                       // RNE
  float r = f - (float)d0;              // exact in fp32
  d1 = (half_t)(r * 4096.0f);           // exact scale; RNE round
}

// force a wave-uniform pointer into SGPRs (frees VGPR pairs per W stream)
__device__ inline const uint4* uni(const uint4* p) {
  uint64_t v = (uint64_t)p;
  uint lo = __builtin_amdgcn_readfirstlane((uint)v);
  uint hi = __builtin_amdgcn_readfirstlane((uint)(v >> 32));
  return (const uint4*)(((uint64_t)hi << 32) | lo);
}

// ---- dtype detector: fp32 storage => low halves of floats are mantissa junk
__global__ void detect_dtype(const unsigned short* __restrict__ x,
                             int* __restrict__ flag) {
  if (blockIdx.x == 0 && threadIdx.x == 0) {
    int f = 0;
    for (int i = 0; i < 256; ++i) {
      float v = bf2f(x[i]);
      if (!(fabsf(v) < 1e10f)) f = 1;   // catches huge, inf, NaN
    }
    *flag = f;
  }
}

// Repack Wc (KTOT x NTOT, row-major) into 2 fp16-digit MFMA B-fragment planes:
// frag index = nt*KB + kb ; element = frag*64 + lane ; lane holds
// B[k = kb*32 + (lane>>4)*8 + j][n = nt*16 + (lane&15)], j=0..7 packed in 16B.
__global__ void repack_wc(const void* __restrict__ Wc,
                          uint4* __restrict__ W0, uint4* __restrict__ W1,
                          const int* __restrict__ flag) {
  int tid = blockIdx.x * blockDim.x + threadIdx.x;  // 40960 threads
  int lane = tid & 63;
  int frag = tid >> 6;                              // 0..639
  int nt = frag / KB;
  int kb = frag - nt * KB;
  int n = nt * 16 + (lane & 15);
  int k0 = kb * 32 + (lane >> 4) * 8;
  int isf = *flag;
  unsigned short e0[8], e1[8];
#pragma unroll
  for (int j = 0; j < 8; ++j) {
    size_t idx = (size_t)(k0 + j) * NTOT + n;
    float w = isf ? ((const float*)Wc)[idx] : bf2f(((const unsigned short*)Wc)[idx]);
    half_t d0, d1;
    split2h(w, d0, d1);
    e0[j] = h2u(d0);
    e1[j] = h2u(d1);
  }
  uint4 o0, o1;
  o0.x = (uint)e0[0] | ((uint)e0[1] << 16);
  o0.y = (uint)e0[2] | ((uint)e0[3] << 16);
  o0.z = (uint)e0[4] | ((uint)e0[5] << 16);
  o0.w = (uint)e0[6] | ((uint)e0[7] << 16);
  o1.x = (uint)e1[0] | ((uint)e1[1] << 16);
  o1.y = (uint)e1[2] | ((uint)e1[3] << 16);
  o1.z = (uint)e1[4] | ((uint)e1[5] << 16);
  o1.w = (uint)e1[6] | ((uint)e1[7] << 16);
  W0[tid] = o0;
  W1[tid] = o1;
}

// 512-thread blocks: the ONLY config the backend ever granted >64 VGPRs
// (round 1: 128). LDS padded past 80 KB (volatile store, un-DCE-able) so one
// block/CU is the hardware max -> 8 waves/CU -> 2 waves/EU -> 256-VGPR
// budget; waves_per_eu(2,2) pins it. The plane-phased pipelined kb-loop needs
// ~204 VGPRs; within budget the scheduler can finally keep 16KB/wave of W
// loads in flight (128KB/CU) instead of serializing them (rounds 2-6, 64-VGPR
// jail, 11ms). DMA path abandoned: round 8 showed global_load_lds is
// L2-hostile (FETCH 183MB -> 9.8GB, HBM-bound 17.6ms).
__global__ __launch_bounds__(THREADS)
__attribute__((amdgpu_waves_per_eu(2, 2))) void xlstm_main(
    const void* __restrict__ xg,
    const void* __restrict__ bc,
    const uint4* __restrict__ W0, const uint4* __restrict__ W1,
    const void* __restrict__ Wa1, const void* __restrict__ ba1,
    const void* __restrict__ Wa2, const void* __restrict__ ba2,
    const void* __restrict__ Wv1, const void* __restrict__ bv1,
    const void* __restrict__ Wv2, const void* __restrict__ bv2,
    void* __restrict__ outv,
    const int* __restrict__ flagp)
{
  __shared__ unsigned short A0[2][ROWS][APAD];   // digit-0 plane [xt | h], dbuf
  __shared__ unsigned short A1[2][ROWS][APAD];   // digit-1 plane (scaled 2^12)
  __shared__ float h32[ROWS][H_ + 4];            // final h in fp32 for the heads
  __shared__ float mida[ROWS][MID_ + 2];
  __shared__ float midv[ROWS][MID_ + 2];
  __shared__ float lgts[ROWS][4];
  __shared__ uint occ_pad[4096];                 // 16 KB occupancy limiter

  const int tid = threadIdx.x;
  ((volatile uint*)occ_pad)[tid] = 0u;           // un-removable: pad stays live

  const int lane = tid & 63;
  const int wave = tid >> 6;                     // 0..7
  const int b0 = blockIdx.x * ROWS;
  const int isf = *flagp;                        // uniform

  // zero h-section of both planes of buffer 0 (h0 = 0)
  {
    int r = tid >> 5;                            // 0..15
    int c0 = 64 + (tid & 31) * 8;                // 64..312
    *(uint4*)&A0[0][r][c0] = make_uint4(0u, 0u, 0u, 0u);
    *(uint4*)&A1[0][r][c0] = make_uint4(0u, 0u, 0u, 0u);
  }

  // x staging: each thread owns 2 consecutive x elements of one row per step
  const int xr = tid >> 5;                       // row 0..15
  const int xc = tid & 31;                       // elem-pair col 0..31
  const uint*  xu_base = (const uint*)xg + ((size_t)(b0 + xr) * T_SEQ) * 32 + xc;
  const float* xf_base = (const float*)xg + ((size_t)(b0 + xr) * T_SEQ) * 64 + xc * 2;
  uint x0, x1;
  {
    float a, b;
    if (isf) { float2 v = *(const float2*)xf_base; a = v.x; b = v.y; }
    else     { uint u = xu_base[0]; a = bf2f((unsigned short)u);
               b = bf2f((unsigned short)(u >> 16)); }
    half_t a0, a1, b0h, b1h;
    split2h(a, a0, a1); split2h(b, b0h, b1h);
    x0 = (uint)h2u(a0) | ((uint)h2u(b0h) << 16);
    x1 = (uint)h2u(a1) | ((uint)h2u(b1h) << 16);
  }

  const int l15 = lane & 15;
  const int quad = lane >> 4;
  const int crow = quad * 4;                     // C-layout row base
  const int u0 = wave * 32 + l15;                // hidden unit, tile pair 0
  const int u1 = u0 + 16;                        // tile pair 1

  const float bi0 = ldin(bc, u0, isf),          bi1 = ldin(bc, u1, isf);
  const float bf0 = ldin(bc, H_ + u0, isf),     bf1 = ldin(bc, H_ + u1, isf);
  const float bo0 = ldin(bc, 2*H_ + u0, isf),   bo1 = ldin(bc, 2*H_ + u1, isf);
  const float bz0 = ldin(bc, 3*H_ + u0, isf),   bz1 = ldin(bc, 3*H_ + u1, isf);

  // W stream bases (wave-uniform, SGPR). Tile i = g*2+tp owns
  // nt = g*16 + wave*2 + tp; frag addr = (nt*KB + kb)*64 + lane.
  const uint4* bp0[8];
  const uint4* bp1[8];
#pragma unroll
  for (int g = 0; g < 4; ++g)
#pragma unroll
    for (int tp = 0; tp < 2; ++tp) {
      const size_t toff = (size_t)((g * 16 + wave * 2 + tp) * KB) * 64;
      bp0[g * 2 + tp] = uni(W0 + toff);
      bp1[g * 2 + tp] = uni(W1 + toff);
    }

  float cst[2][4], nst[2][4];
#pragma unroll
  for (int tp = 0; tp < 2; ++tp)
#pragma unroll
    for (int r = 0; r < 4; ++r) { cst[tp][r] = 0.f; nst[tp][r] = 1.f; }

  // preload kb=0 of the W0 plane, all 8 tiles (per-lane offset lane*16 B)
  uint koff = (uint)lane * 16u;
  uint4 w0c[8];
#pragma unroll
  for (int i = 0; i < 8; ++i)
    w0c[i] = *(const uint4*)((const char*)bp0[i] + koff);

  for (int t = 0; t < T_SEQ; ++t) {
    const int cur = t & 1, nxt = cur ^ 1;
    *(uint*)&A0[cur][xr][xc * 2] = x0;           // write x(t) digits
    *(uint*)&A1[cur][xr][xc * 2] = x1;
    // LDS-only barrier: drain lgkm (ds writes visible), NOT vmcnt, so W
    // prefetch loads stay in flight across the step boundary.
    asm volatile("s_waitcnt lgkmcnt(0)\n\ts_barrier" ::: "memory");

    // issue x(t+1) raw load now; split AFTER the GEMM (no early vmcnt drain)
    float xaf = 0.f, xbf = 0.f; uint xau = 0;
    if (t + 1 < T_SEQ) {
      if (isf) { float2 v = *(const float2*)(xf_base + (size_t)(t + 1) * 64);
                 xaf = v.x; xbf = v.y; }
      else     { xau = xu_base[(size_t)(t + 1) * 32]; }
    }

    // gates GEMM, 2-digit fp16 split with scaled-residual planes:
    //   gate = (a0·w0) + 2^-12 · (a0·w1' + a1'·w0)     [a1'w1' ~2^-24, dropped]
    // Plane-phased pipeline per kb: issue W1[kb] (8 tiles) | 16 MFMAs on
    // W0[kb] | issue W0[kb+1] | 8 MFMAs on W1[kb].  Peak live ~204 VGPRs.
    // Per-accumulator order identical to the verified kernel:
    //   accA: fa0*w0 kb-ascending; accB: per kb fa1*w0 then fa0*w1.
    floatx4 accA[4][2], accB[4][2];
#pragma unroll
    for (int g = 0; g < 4; ++g)
#pragma unroll
      for (int tp = 0; tp < 2; ++tp) {
        accA[g][tp] = (floatx4){0.f, 0.f, 0.f, 0.f};
        accB[g][tp] = (floatx4){0.f, 0.f, 0.f, 0.f};
      }
#pragma unroll
    for (int kb = 0; kb < KB; ++kb) {
      const half8 fa0 = u4h8(*(const uint4*)&A0[cur][l15][kb * 32 + quad * 8]);
      const half8 fa1 = u4h8(*(const uint4*)&A1[cur][l15][kb * 32 + quad * 8]);
      // issue W1[kb] for all 8 tiles (consumed at the tail of this kb)
      uint4 w1c[8];
#pragma unroll
      for (int i = 0; i < 8; ++i)
        w1c[i] = *(const uint4*)((const char*)bp1[i] + koff);
      // 16 MFMAs on W0[kb]
#pragma unroll
      for (int g = 0; g < 4; ++g)
#pragma unroll
        for (int tp = 0; tp < 2; ++tp)
          accA[g][tp] = __builtin_amdgcn_mfma_f32_16x16x32_f16(
              fa0, u4h8(w0c[g * 2 + tp]), accA[g][tp], 0, 0, 0);
#pragma unroll
      for (int g = 0; g < 4; ++g)
#pragma unroll
        for (int tp = 0; tp < 2; ++tp)
          accB[g][tp] = __builtin_amdgcn_mfma_f32_16x16x32_f16(
              fa1, u4h8(w0c[g * 2 + tp]), accB[g][tp], 0, 0, 0);
      // issue W0[kb+1] (wraps to kb=0 of the NEXT step at kb==9 so its
      // latency hides under the sLSTM update + barrier)
      const uint koff2 = (kb < KB - 1) ? (koff + 1024u) : ((uint)lane * 16u);
      uint4 w0n[8];
#pragma unroll
      for (int i = 0; i < 8; ++i)
        w0n[i] = *(const uint4*)((const char*)bp0[i] + koff2);
      // 8 MFMAs on W1[kb]
#pragma unroll
      for (int g = 0; g < 4; ++g)
#pragma unroll
        for (int tp = 0; tp < 2; ++tp)
          accB[g][tp] = __builtin_amdgcn_mfma_f32_16x16x32_f16(
              fa0, u4h8(w1c[g * 2 + tp]), accB[g][tp], 0, 0, 0);
      // rotate (SSA renames under full unroll)
#pragma unroll
      for (int i = 0; i < 8; ++i) w0c[i] = w0n[i];
      koff = koff2;
    }

    // split the prefetched x(t+1) — its latency hid under the whole GEMM
    if (t + 1 < T_SEQ) {
      float a, b;
      if (isf) { a = xaf; b = xbf; }
      else     { a = bf2f((unsigned short)xau);
                 b = bf2f((unsigned short)(xau >> 16)); }
      half_t a0, a1, b0h, b1h;
      split2h(a, a0, a1); split2h(b, b0h, b1h);
      x0 = (uint)h2u(a0) | ((uint)h2u(b0h) << 16);
      x1 = (uint)h2u(a1) | ((uint)h2u(b1h) << 16);
    }

    // sLSTM update, all in registers (lane owns 8 (row,unit) pairs)
#pragma unroll
    for (int tp = 0; tp < 2; ++tp) {
      const float bi = tp ? bi1 : bi0;
      const float bf = tp ? bf1 : bf0;
      const float bo = tp ? bo1 : bo0;
      const float bz = tp ? bz1 : bz0;
      const int unit = tp ? u1 : u0;
#pragma unroll
      for (int r = 0; r < 4; ++r) {
        float gi = accA[0][tp][r] + accB[0][tp][r] * INV4096 + bi;
        float gf = accA[1][tp][r] + accB[1][tp][r] * INV4096 + bf;
        float ov = accA[2][tp][r] + accB[2][tp][r] * INV4096 + bo;
        float zv = accA[3][tp][r] + accB[3][tp][r] * INV4096 + bz;
        float iv = __expf(fminf(fmaxf(gi, -5.f), 5.f));
        float fv = __expf(fminf(fmaxf(gf, -5.f), 5.f));
        float e2z = __expf(2.f * zv);
        float tz = 1.f - 2.f / (e2z + 1.f);      // tanh, exact div
        float cv = fv * cst[tp][r] + iv * tz;
        cv = fminf(fmaxf(cv, -1e6f), 1e6f);
        float nv = fv * nst[tp][r] + iv;
        nv = fminf(fmaxf(nv, 1e-6f), 1e6f);
        cst[tp][r] = cv; nst[tp][r] = nv;
        float sg = 1.f / (1.f + __expf(-ov));    // sigmoid, exact div
        float hv = sg * (cv / nv);
        if (!(fabsf(hv) < 1e37f)) hv = 0.f;      // nan_to_num(nan/±inf -> 0)
        half_t d0, d1;
        split2h(hv, d0, d1);
        A0[nxt][crow + r][64 + unit] = h2u(d0);
        A1[nxt][crow + r][64 + unit] = h2u(d1);
        if (t == T_SEQ - 1) h32[crow + r][unit] = hv;
      }
    }
  }
  __syncthreads();                               // full drain before heads

  // ---- heads (fp32 VALU, one-time) ----
#pragma unroll
  for (int it = 0; it < 2; ++it) {
    int idx = tid + it * THREADS;                // 0..1023
    int r = idx >> 6, m = idx & 63;
    float sa = ldin(ba1, m, isf);
    float sv = ldin(bv1, m, isf);
    for (int k = 0; k < H_; ++k) {
      float hv = h32[r][k];
      sa += hv * ldin(Wa1, k * MID_ + m, isf);
      sv += hv * ldin(Wv1, k * MID_ + m, isf);
    }
    mida[r][m] = fmaxf(sa, 0.f);
    midv[r][m] = fmaxf(sv, 0.f);
  }
  __syncthreads();
  if (tid < ROWS * 4) {
    int r = tid >> 2, j = tid & 3;
    if (j < 3) {
      float s = ldin(ba2, j, isf);
      for (int m = 0; m < MID_; ++m) s += mida[r][m] * ldin(Wa2, m * ACT_ + j, isf);
      lgts[r][j] = s;
    } else {
      float s = ldin(bv2, 0, isf);
      for (int m = 0; m < MID_; ++m) s += midv[r][m] * ldin(Wv2, m, isf);
      int oi = 3 * B_TOT + b0 + r;               // value output
      if (isf) ((float*)outv)[oi] = s; else ((unsigned short*)outv)[oi] = 0;
    }
  }
  __syncthreads();
  if (tid < ROWS) {
    float l0 = lgts[tid][0], l1 = lgts[tid][1], l2 = lgts[tid][2];
    float mx = fmaxf(l0, fmaxf(l1, l2));
    float e0 = __expf(l0 - mx), e1 = __expf(l1 - mx), e2 = __expf(l2 - mx);
    float inv = 1.f / (e0 + e1 + e2);
    int oi = (b0 + tid) * 3;
    ((float*)outv)[oi + 0] = e0 * inv;
    ((float*)outv)[oi + 1] = e1 * inv;
    ((float*)outv)[oi + 2] = e2 * inv;
  }
}

extern "C" void kernel_launch(void* const* d_in, const int* in_sizes, int n_in,
                              void* d_out, int out_size, void* d_ws, size_t ws_size,
                              hipStream_t stream) {
  const void* x   = d_in[0];
  const void* Wc  = d_in[1];
  const void* bc  = d_in[2];
  const void* Wa1 = d_in[3];
  const void* ba1 = d_in[4];
  const void* Wa2 = d_in[5];
  const void* ba2 = d_in[6];
  const void* Wv1 = d_in[7];
  const void* bv1 = d_in[8];
  const void* Wv2 = d_in[9];
  const void* bv2 = d_in[10];

  int*   flag = (int*)d_ws;
  uint4* W0p  = (uint4*)((char*)d_ws + WP0_OFF);   // 640 KB digit-0 plane
  uint4* W1p  = (uint4*)((char*)d_ws + WP1_OFF);   // 640 KB scaled digit-1 plane

  detect_dtype<<<1, 64, 0, stream>>>((const unsigned short*)x, flag);
  repack_wc<<<160, 256, 0, stream>>>(Wc, W0p, W1p, flag);
  xlstm_main<<<NBLK, THREADS, 0, stream>>>(x, bc, W0p, W1p,
                                           Wa1, ba1, Wa2, ba2,
                                           Wv1, bv1, Wv2, bv2, d_out, flag);
}

// Round 11
// 5786.436 us; speedup vs baseline: 3.0507x; 2.4921x over previous
//
#include <hip/hip_runtime.h>
#include <stdint.h>

typedef unsigned int uint;
typedef unsigned long long u64;

#define T_SEQ 512
#define D_IN 64
#define H_ 256
#define KTOT 320      // D_IN + H_
#define NTOT 1024     // 4*H_
#define MID_ 64
#define ACT_ 3
#define B_TOT 1024
#define ROWS 16       // batch rows per block
#define NBLK 64
#define THREADS 1024  // 16 waves, 4 waves/SIMD
#define KB 10         // K blocks of 32 (320/32)
#define APAD 328      // padded A-row stride (elements)
#define WP_ELEMS 40960                  // uint4 per weight plane (64 nt * 10 kb * 64)
#define WP_BYTES (WP_ELEMS * 16)        // 640 KB per plane
#define WP0_OFF 1024
#define WP1_OFF (WP0_OFF + WP_BYTES)
#define INV4096 2.44140625e-4f          // 2^-12

typedef _Float16 half_t;
typedef __attribute__((ext_vector_type(8))) _Float16 half8;
typedef __attribute__((ext_vector_type(4))) float floatx4;

__device__ inline float bf2f(unsigned short s) {
  union { uint u; float f; } v; v.u = ((uint)s) << 16; return v.f;
}
union UHU { half_t h; unsigned short u; };
__device__ inline unsigned short h2u(half_t h) { UHU v; v.h = h; return v.u; }
union U4H8 { uint4 u; half8 h; };
__device__ inline half8 u4h8(uint4 v) { U4H8 t; t.u = v; return t.h; }

// load input element idx as float, from fp32 or bf16 storage
__device__ inline float ldin(const void* p, int idx, int isf) {
  return isf ? ((const float*)p)[idx] : bf2f(((const unsigned short*)p)[idx]);
}

// 2-digit fp16 split with scaled residual: f ≈ d0 + d1*2^-12, rel err ~2^-22.
__device__ inline void split2h(float f, half_t& d0, half_t& d1) {
  d0 = (half_t)f;                       // RNE
  float r = f - (float)d0;              // exact in fp32
  d1 = (half_t)(r * 4096.0f);           // exact scale; RNE round
}

// force a wave-uniform pointer into SGPRs
__device__ inline u64 uni64(const void* p) {
  u64 v = (u64)p;
  uint lo = __builtin_amdgcn_readfirstlane((uint)v);
  uint hi = __builtin_amdgcn_readfirstlane((uint)(v >> 32));
  return ((u64)hi << 32) | lo;
}

// inline-asm W load: SGPR base + per-lane voffset, counted by MY vmcnt waits.
// The compiler cannot sink these (volatile asm keeps program order among asm)
// and MUST allocate the dest quad -> forces a real register pipeline.
// odd is compile-time: selects the +1024B immediate-offset form.
__device__ __forceinline__ void wload(uint4& d, u64 base, uint voff, int odd) {
  if (odd) asm volatile("global_load_dwordx4 %0, %1, %2 offset:1024"
                        : "=v"(d) : "v"(voff), "s"(base));
  else     asm volatile("global_load_dwordx4 %0, %1, %2"
                        : "=v"(d) : "v"(voff), "s"(base));
}

// ---- dtype detector: fp32 storage => low halves of floats are mantissa junk
__global__ void detect_dtype(const unsigned short* __restrict__ x,
                             int* __restrict__ flag) {
  if (blockIdx.x == 0 && threadIdx.x == 0) {
    int f = 0;
    for (int i = 0; i < 256; ++i) {
      float v = bf2f(x[i]);
      if (!(fabsf(v) < 1e10f)) f = 1;   // catches huge, inf, NaN
    }
    *flag = f;
  }
}

// Repack Wc (KTOT x NTOT, row-major) into 2 fp16-digit MFMA B-fragment planes:
// frag index = nt*KB + kb ; element = frag*64 + lane ; lane holds
// B[k = kb*32 + (lane>>4)*8 + j][n = nt*16 + (lane&15)], j=0..7 packed in 16B.
__global__ void repack_wc(const void* __restrict__ Wc,
                          uint4* __restrict__ W0, uint4* __restrict__ W1,
                          const int* __restrict__ flag) {
  int tid = blockIdx.x * blockDim.x + threadIdx.x;  // 40960 threads
  int lane = tid & 63;
  int frag = tid >> 6;                              // 0..639
  int nt = frag / KB;
  int kb = frag - nt * KB;
  int n = nt * 16 + (lane & 15);
  int k0 = kb * 32 + (lane >> 4) * 8;
  int isf = *flag;
  unsigned short e0[8], e1[8];
#pragma unroll
  for (int j = 0; j < 8; ++j) {
    size_t idx = (size_t)(k0 + j) * NTOT + n;
    float w = isf ? ((const float*)Wc)[idx] : bf2f(((const unsigned short*)Wc)[idx]);
    half_t d0, d1;
    split2h(w, d0, d1);
    e0[j] = h2u(d0);
    e1[j] = h2u(d1);
  }
  uint4 o0, o1;
  o0.x = (uint)e0[0] | ((uint)e0[1] << 16);
  o0.y = (uint)e0[2] | ((uint)e0[3] << 16);
  o0.z = (uint)e0[4] | ((uint)e0[5] << 16);
  o0.w = (uint)e0[6] | ((uint)e0[7] << 16);
  o1.x = (uint)e1[0] | ((uint)e1[1] << 16);
  o1.y = (uint)e1[2] | ((uint)e1[3] << 16);
  o1.z = (uint)e1[4] | ((uint)e1[5] << 16);
  o1.w = (uint)e1[6] | ((uint)e1[7] << 16);
  W0[tid] = o0;
  W1[tid] = o1;
}

// Inline-asm W pipeline: 40 groups/step of 2x global_load_dwordx4 into a
// 5-slot register ring (40%5==0 -> slot map is continuous across steps),
// 4 groups (8KB/wave, 128KB/CU) always in flight, counted vmcnt(8) per phase.
// Rounds 2-10 proved the compiler NEVER pipelines VGPR-destined loads here on
// its own (VGPR jailed at 64/128, loads sunk to use, 11-14ms); round 8 proved
// global_load_lds is L2-hostile (FETCH x54). Plain VGPR loads are L2-resident
// (FETCH ~183MB) -> force the pipeline by hand.
__global__ __launch_bounds__(THREADS) void xlstm_main(
    const void* __restrict__ xg,
    const void* __restrict__ bc,
    const uint4* __restrict__ W0, const uint4* __restrict__ W1,
    const void* __restrict__ Wa1, const void* __restrict__ ba1,
    const void* __restrict__ Wa2, const void* __restrict__ ba2,
    const void* __restrict__ Wv1, const void* __restrict__ bv1,
    const void* __restrict__ Wv2, const void* __restrict__ bv2,
    void* __restrict__ outv,
    const int* __restrict__ flagp)
{
  __shared__ unsigned short A0[2][ROWS][APAD];   // digit-0 plane [xt | h], dbuf
  __shared__ unsigned short A1[2][ROWS][APAD];   // digit-1 plane (scaled 2^12)
  __shared__ float h32[ROWS][H_ + 4];            // final h in fp32 for the heads
  __shared__ float mida[ROWS][MID_ + 2];
  __shared__ float midv[ROWS][MID_ + 2];
  __shared__ float lgts[ROWS][4];
  __shared__ uint occ_pad[4096];                 // 16 KB: hard 1 block/CU

  const int tid = threadIdx.x;
  ((volatile uint*)occ_pad)[tid] = 0u;           // un-removable pad

  const int lane = tid & 63;
  const int wave = tid >> 6;                     // 0..15
  const int b0 = blockIdx.x * ROWS;
  const int isf = *flagp;                        // uniform

  // zero h-section of both planes of buffer 0 (h0 = 0): 4 shorts per thread
  {
    int r = tid >> 6;                            // 0..15
    int c0 = 64 + (tid & 63) * 4;                // 64..316
    *(uint2*)&A0[0][r][c0] = make_uint2(0u, 0u);
    *(uint2*)&A1[0][r][c0] = make_uint2(0u, 0u);
  }

  // x staging: each thread owns exactly 1 x element of one row per step
  const int xr = tid >> 6;                       // row 0..15
  const int xcol = tid & 63;                     // col 0..63
  const unsigned short* xu_base =
      (const unsigned short*)xg + ((size_t)(b0 + xr) * T_SEQ) * 64 + xcol;
  const float* xf_base =
      (const float*)xg + ((size_t)(b0 + xr) * T_SEQ) * 64 + xcol;
  // initial x(0): plain C load, fully drained BEFORE any counted W load issues
  unsigned short x0, x1;
  {
    float a = isf ? xf_base[0] : bf2f(xu_base[0]);
    half_t d0, d1;
    split2h(a, d0, d1);
    x0 = h2u(d0); x1 = h2u(d1);
  }
  const u64 xb = isf ? (u64)xf_base : (u64)xu_base;
  const uint xstr = isf ? 256u : 128u;           // bytes per timestep

  const int l15 = lane & 15;
  const int quad = lane >> 4;
  const int crow = quad * 4;                     // C-layout row base
  const int u = wave * 16 + l15;                 // hidden unit owned by this lane

  const float bi  = ldin(bc, u, isf);
  const float bfg = ldin(bc, H_ + u, isf);
  const float bo  = ldin(bc, 2 * H_ + u, isf);
  const float bz  = ldin(bc, 3 * H_ + u, isf);

  // W bases (SGPR pairs). Wave owns tiles nt = g*16 + wave, g=0..3.
  u64 b0a[4], b1a[4];
#pragma unroll
  for (int g = 0; g < 4; ++g) {
    const size_t toff = (size_t)((g * 16 + wave) * KB) * 64;
    b0a[g] = uni64(W0 + toff);
    b1a[g] = uni64(W1 + toff);
  }
  // per-lane voffsets: vk[h] = lane*16 + (2h)*1024; odd kb adds offset:1024
  uint vk[5];
#pragma unroll
  for (int h = 0; h < 5; ++h) vk[h] = (uint)lane * 16u + (uint)h * 2048u;

  float cst[4], nst[4];
#pragma unroll
  for (int r = 0; r < 4; ++r) { cst[r] = 0.f; nst[r] = 1.f; }

  // 5-slot register ring. group j (j=0..39 per step): kb=j>>2, sub=j&3;
  // sub0=W0 tiles{0,1}, sub1=W0 tiles{2,3}, sub2=W1{0,1}, sub3=W1{2,3}.
  uint4 wbuf[5][2];
  // prologue: issue groups 0..3 (kb=0) into slots 0..3
#pragma unroll
  for (int j = 0; j < 4; ++j) {
    const int pl = j >> 1, tb = (j & 1) * 2;
    wload(wbuf[j][0], pl ? b1a[tb] : b0a[tb], vk[0], 0);
    wload(wbuf[j][1], pl ? b1a[tb + 1] : b0a[tb + 1], vk[0], 0);
  }

  for (int t = 0; t < T_SEQ; ++t) {
    const int cur = t & 1, nxt = cur ^ 1;
    A0[cur][xr][xcol] = x0;                      // write x(t) digits
    A1[cur][xr][xcol] = x1;
    // LDS-only barrier: drain lgkm, NOT vmcnt — W pipeline survives the step
    asm volatile("s_waitcnt lgkmcnt(0)\n\ts_barrier" ::: "memory");

    // x(t+1) via inline asm so it has a known slot in the vmcnt stream
    // (absorbed by the vmcnt(9) at phase 0 / vmcnt(8) at phase 1)
    uint xw = 0;
    {
      const int tn = (t + 1 < T_SEQ) ? (t + 1) : t;
      u64 xp = xb + (u64)tn * xstr;
      if (isf) asm volatile("global_load_dword %0, %1, off"
                            : "=v"(xw) : "v"(xp));
      else     asm volatile("global_load_ushort %0, %1, off"
                            : "=v"(xw) : "v"(xp));
    }

    // gates GEMM, 2-digit fp16 split with scaled-residual planes:
    //   gate = (a0·w0) + 2^-12 · (a0·w1' + a1'·w0)     [a1'w1' ~2^-24, dropped]
    // Per-accumulator MFMA order identical to all passing rounds:
    //   accA[g]: fa0*W0[kb] kb-ascending; accB[g]: fa1*W0[kb] then fa0*W1[kb].
    floatx4 accA[4], accB[4];
#pragma unroll
    for (int g = 0; g < 4; ++g) {
      accA[g] = (floatx4){0.f, 0.f, 0.f, 0.f};
      accB[g] = (floatx4){0.f, 0.f, 0.f, 0.f};
    }
    half8 fa0 = {}, fa1 = {};
#pragma unroll
    for (int j = 0; j < 40; ++j) {
      const int kb = j >> 2, sub = j & 3;
      if (sub == 0) {                            // fragments for this kb
        fa0 = u4h8(*(const uint4*)&A0[cur][l15][kb * 32 + quad * 8]);
        fa1 = u4h8(*(const uint4*)&A1[cur][l15][kb * 32 + quad * 8]);
      }
      // issue group j+4 (wraps to next step's groups 0..3; W is t-invariant)
      {
        const int jn = (j + 4) % 40;
        const int kbn = jn >> 2, subn = jn & 3, sn = (j + 4) % 5;
        const int pl = subn >> 1, tb = (subn & 1) * 2;
        const uint vo = vk[kbn >> 1];
        const int odd = kbn & 1;
        wload(wbuf[sn][0], pl ? b1a[tb] : b0a[tb], vo, odd);
        wload(wbuf[sn][1], pl ? b1a[tb + 1] : b0a[tb + 1], vo, odd);
      }
      // wait for group j (4 groups = 8 loads stay outstanding; phase 0 also
      // tolerates the x load in the stream)
      if (j == 0) asm volatile("s_waitcnt vmcnt(9)" ::: "memory");
      else        asm volatile("s_waitcnt vmcnt(8)" ::: "memory");
      __builtin_amdgcn_sched_barrier(0);         // rule 18: pin MFMAs below
      // consume group j from slot j%5
      {
        const int s = j % 5;
        const int tb = (sub & 1) * 2;
        const half8 w0f = u4h8(wbuf[s][0]);
        const half8 w1f = u4h8(wbuf[s][1]);
        if (sub < 2) {                           // W0 plane
          accA[tb]     = __builtin_amdgcn_mfma_f32_16x16x32_f16(fa0, w0f, accA[tb],     0, 0, 0);
          accA[tb + 1] = __builtin_amdgcn_mfma_f32_16x16x32_f16(fa0, w1f, accA[tb + 1], 0, 0, 0);
          accB[tb]     = __builtin_amdgcn_mfma_f32_16x16x32_f16(fa1, w0f, accB[tb],     0, 0, 0);
          accB[tb + 1] = __builtin_amdgcn_mfma_f32_16x16x32_f16(fa1, w1f, accB[tb + 1], 0, 0, 0);
        } else {                                 // W1 plane
          accB[tb]     = __builtin_amdgcn_mfma_f32_16x16x32_f16(fa0, w0f, accB[tb],     0, 0, 0);
          accB[tb + 1] = __builtin_amdgcn_mfma_f32_16x16x32_f16(fa0, w1f, accB[tb + 1], 0, 0, 0);
        }
      }
    }

    // split the prefetched x(t+1) — retired by the early-phase vmcnt waits
    if (t + 1 < T_SEQ) {
      float a;
      if (isf) { union { uint u; float f; } c; c.u = xw; a = c.f; }
      else     a = bf2f((unsigned short)xw);
      half_t d0, d1;
      split2h(a, d0, d1);
      x0 = h2u(d0); x1 = h2u(d1);
    }

    // sLSTM update, all in registers (lane owns 4 (row,unit) pairs)
#pragma unroll
    for (int r = 0; r < 4; ++r) {
      float gi = accA[0][r] + accB[0][r] * INV4096 + bi;
      float gf = accA[1][r] + accB[1][r] * INV4096 + bfg;
      float ov = accA[2][r] + accB[2][r] * INV4096 + bo;
      float zv = accA[3][r] + accB[3][r] * INV4096 + bz;
      float iv = __expf(fminf(fmaxf(gi, -5.f), 5.f));
      float fv = __expf(fminf(fmaxf(gf, -5.f), 5.f));
      float e2z = __expf(2.f * zv);
      float tz = 1.f - 2.f / (e2z + 1.f);        // tanh, exact div
      float cv = fv * cst[r] + iv * tz;
      cv = fminf(fmaxf(cv, -1e6f), 1e6f);
      float nv = fv * nst[r] + iv;
      nv = fminf(fmaxf(nv, 1e-6f), 1e6f);
      cst[r] = cv; nst[r] = nv;
      float sg = 1.f / (1.f + __expf(-ov));      // sigmoid, exact div
      float hv = sg * (cv / nv);
      if (!(fabsf(hv) < 1e37f)) hv = 0.f;        // nan_to_num(nan/±inf -> 0)
      half_t d0, d1;
      split2h(hv, d0, d1);
      A0[nxt][crow + r][64 + u] = h2u(d0);
      A1[nxt][crow + r][64 + u] = h2u(d1);
      if (t == T_SEQ - 1) h32[crow + r][u] = hv;
    }
  }
  __syncthreads();                               // full drain before heads

  // ---- heads (fp32 VALU, one-time) ----
  {
    int r = tid >> 6, m = tid & 63;              // 1024 threads = 16 rows x 64
    float sa = ldin(ba1, m, isf);
    float sv = ldin(bv1, m, isf);
    for (int k = 0; k < H_; ++k) {
      float hv = h32[r][k];
      sa += hv * ldin(Wa1, k * MID_ + m, isf);
      sv += hv * ldin(Wv1, k * MID_ + m, isf);
    }
    mida[r][m] = fmaxf(sa, 0.f);
    midv[r][m] = fmaxf(sv, 0.f);
  }
  __syncthreads();
  if (tid < ROWS * 4) {
    int r = tid >> 2, j = tid & 3;
    if (j < 3) {
      float s = ldin(ba2, j, isf);
      for (int m = 0; m < MID_; ++m) s += mida[r][m] * ldin(Wa2, m * ACT_ + j, isf);
      lgts[r][j] = s;
    } else {
      float s = ldin(bv2, 0, isf);
      for (int m = 0; m < MID_; ++m) s += midv[r][m] * ldin(Wv2, m, isf);
      int oi = 3 * B_TOT + b0 + r;               // value output
      if (isf) ((float*)outv)[oi] = s; else ((unsigned short*)outv)[oi] = 0;
    }
  }
  __syncthreads();
  if (tid < ROWS) {
    float l0 = lgts[tid][0], l1 = lgts[tid][1], l2 = lgts[tid][2];
    float mx = fmaxf(l0, fmaxf(l1, l2));
    float e0 = __expf(l0 - mx), e1 = __expf(l1 - mx), e2 = __expf(l2 - mx);
    float inv = 1.f / (e0 + e1 + e2);
    int oi = (b0 + tid) * 3;
    ((float*)outv)[oi + 0] = e0 * inv;
    ((float*)outv)[oi + 1] = e1 * inv;
    ((float*)outv)[oi + 2] = e2 * inv;
  }
}

extern "C" void kernel_launch(void* const* d_in, const int* in_sizes, int n_in,
                              void* d_out, int out_size, void* d_ws, size_t ws_size,
                              hipStream_t stream) {
  const void* x   = d_in[0];
  const void* Wc  = d_in[1];
  const void* bc  = d_in[2];
  const void* Wa1 = d_in[3];
  const void* ba1 = d_in[4];
  const void* Wa2 = d_in[5];
  const void* ba2 = d_in[6];
  const void* Wv1 = d_in[7];
  const void* bv1 = d_in[8];
  const void* Wv2 = d_in[9];
  const void* bv2 = d_in[10];

  int*   flag = (int*)d_ws;
  uint4* W0p  = (uint4*)((char*)d_ws + WP0_OFF);   // 640 KB digit-0 plane
  uint4* W1p  = (uint4*)((char*)d_ws + WP1_OFF);   // 640 KB scaled digit-1 plane

  detect_dtype<<<1, 64, 0, stream>>>((const unsigned short*)x, flag);
  repack_wc<<<160, 256, 0, stream>>>(Wc, W0p, W1p, flag);
  xlstm_main<<<NBLK, THREADS, 0, stream>>>(x, bc, W0p, W1p,
                                           Wa1, ba1, Wa2, ba2,
                                           Wv1, bv1, Wv2, bv2, d_out, flag);
}